// Round 11
// baseline (32.062 us; speedup 1.0000x reference)
//
#include <hip/hip_runtime.h>

// Problem constants (b=4, n=64, d=64, E=4096)
// zt  layout: [b][d][i][k] -> ((b*64+d)*64+i)*64+k   (4 MB)
// zt2: tropical output, same layout (4 MB)
// a1[r][e], a3[r][e] : r = b*64+i (node row), 64 KB each
//
// R11 = R9 geometry (3 dispatches, 256 blocks x 1024 thr) with:
//  - broadcast operand: LDS ds_read_b128 wave-uniform (proven R9)
//  - per-lane operand: registers from coalesced GLOBAL loads (proven R7)
//    -> DS pipe budget per wave halves (64 b128, zero b32 in compute loops)
//  - K1 lane=k mapping -> z stores are coalesced 256B (was 64x16B scatter)

// K1: z = pe@Whz + bhz (transposed store) + node MLP + nodeproj. grid = 256 (bi)
// lane = k; wave w owns d in [w*4, w*4+4). Broadcast = Whz (LDS).
__global__ __launch_bounds__(1024) void k_pathlin_node(
    const float* __restrict__ ne, const float* __restrict__ pe,
    const int* __restrict__ eidx,
    const float* __restrict__ Whz, const float* __restrict__ bhz,
    const float* __restrict__ Wzz,
    const float* __restrict__ Wnm, const float* __restrict__ bnm,
    float* __restrict__ zt, float* __restrict__ a1, float* __restrict__ a3,
    float* __restrict__ out0) {
  int bi = blockIdx.x;                    // b*64 + i == node row
  int b = bi >> 6, i = bi & 63;
  int t = threadIdx.x, lane = t & 63, w = t >> 6;
  int d0 = w * 4;
  __shared__ float sW[4096];              // Whz [c][d], 16KB
  __shared__ int elist[4096];             // node tail
  __shared__ float part[16][64];
  __shared__ float nl[64], al[64];
  // stage Whz once (coalesced)
  ((float4*)sW)[t] = ((const float4*)Whz)[t];
  // per-lane pe row: pr[c4] = pe[bi][k=lane][c4*4..+3] (same 64B line across c4)
  const float* peb = pe + (size_t)bi * 4096 + (size_t)lane * 64;
  float4 pr[16];
#pragma unroll
  for (int c4 = 0; c4 < 16; ++c4) pr[c4] = *(const float4*)(peb + c4 * 4);
  float acc[4] = {bhz[d0], bhz[d0 + 1], bhz[d0 + 2], bhz[d0 + 3]};
  __syncthreads();
#pragma unroll
  for (int c = 0; c < 64; ++c) {
    const float4 wv = *(const float4*)&sW[c * 64 + d0];   // broadcast b128
    float pv = (c & 2) ? ((c & 1) ? pr[c >> 2].w : pr[c >> 2].z)
                       : ((c & 1) ? pr[c >> 2].y : pr[c >> 2].x);
    acc[0] += pv * wv.x;
    acc[1] += pv * wv.y;
    acc[2] += pv * wv.z;
    acc[3] += pv * wv.w;
  }
  // coalesced store: zt[b][d0+dd][i][k=lane], 256B per dd
  float* zb = zt + (size_t)b * 262144 + (size_t)i * 64 + lane;
#pragma unroll
  for (int dd = 0; dd < 4; ++dd) zb[(size_t)(d0 + dd) * 4096] = acc[dd];

  // ---- node MLP row bi (R9-proven) ----
  if (w == 0) nl[lane] = ne[bi * 64 + lane];
  const int* srcv = eidx;
  const int* dstv = eidx + 4096;
  int cntw = 0;
  unsigned long long ltmask = (lane == 63) ? 0x7fffffffffffffffull
                                           : ((1ull << lane) - 1ull);
#pragma unroll
  for (int q = 0; q < 4; ++q) {
    int e2 = w * 256 + q * 64 + lane;
    bool match = (dstv[e2] == bi);
    unsigned long long mask = __ballot(match);
    if (match) {
      int pos = cntw + __popcll(mask & ltmask);
      elist[w * 256 + pos] = srcv[e2];
    }
    cntw += __popcll(mask);
  }
  float accA = 0.f;
  for (int m = 0; m < cntw; ++m) accA += ne[elist[w * 256 + m] * 64 + lane];
  part[w][lane] = accA;
  __syncthreads();
  if (w == 0) {
    float s = 0.f;
#pragma unroll
    for (int p2 = 0; p2 < 16; ++p2) s += part[p2][lane];
    al[lane] = s;
  } else if (w == 2) {                    // nodeproj a1
    const float* nr = ne + bi * 64;
    float s1 = 0.f;
    for (int d2 = 0; d2 < 64; ++d2) s1 += nr[d2] * Wzz[d2 * 64 + lane];
    a1[bi * 64 + lane] = s1;
  } else if (w == 3) {                    // nodeproj a3
    const float* nr = ne + bi * 64;
    float s3 = 0.f;
    for (int d2 = 0; d2 < 64; ++d2) s3 += nr[d2] * Wzz[(128 + d2) * 64 + lane];
    a3[bi * 64 + lane] = s3;
  }
  __syncthreads();
  {
    float s = 0.f;
#pragma unroll
    for (int dd = 0; dd < 4; ++dd) {
      int d2 = w * 4 + dd;
      s += nl[d2] * Wnm[d2 * 64 + lane] + al[d2] * Wnm[(64 + d2) * 64 + lane];
    }
    part[w][lane] = s;
  }
  __syncthreads();
  if (w == 0) {
    float v = bnm[lane];
#pragma unroll
    for (int p2 = 0; p2 < 16; ++p2) v += part[p2][lane];
    v = fmaxf(v, 0.f);
    out0[bi * 64 + lane] = v + nl[lane];
  }
}

// K2: tropical max-plus per (b,d) slice. grid = 256 (slice)
// lane = j; wave w owns rows [w*4, w*4+4). Broadcast = rows (LDS);
// per-lane column + acc-init from global (coalesced, L1-hot).
__global__ __launch_bounds__(1024) void k_tropical(
    const float* __restrict__ zt, float* __restrict__ zt2) {
  int slice = blockIdx.x;                 // b*64 + d
  int t = threadIdx.x, lane = t & 63, w = t >> 6;
  __shared__ float A[4096];               // 16KB slice for row broadcasts
  const float* Ag = zt + (size_t)slice * 4096;
  ((float4*)A)[t] = ((const float4*)Ag)[t];
  // per-lane column from global: colreg[k] = A[k][j=lane] (coalesced, L1-hot)
  float colreg[64];
#pragma unroll
  for (int k = 0; k < 64; ++k) colreg[k] = Ag[k * 64 + lane];
  int i0 = w * 4;
  float acc[4];
#pragma unroll
  for (int ii = 0; ii < 4; ++ii) acc[ii] = Ag[(i0 + ii) * 64 + lane];  // max(zc,z)
  __syncthreads();
#pragma unroll
  for (int k = 0; k < 64; k += 4) {
#pragma unroll
    for (int ii = 0; ii < 4; ++ii) {
      const float4 a = *(const float4*)&A[(i0 + ii) * 64 + k];   // broadcast b128
      float m0 = fmaxf(a.x + colreg[k], a.y + colreg[k + 1]);
      float m1 = fmaxf(a.z + colreg[k + 2], a.w + colreg[k + 3]);
      acc[ii] = fmaxf(acc[ii], fmaxf(m0, m1));
    }
  }
  float* Og = zt2 + (size_t)slice * 4096 + (size_t)i0 * 64;
#pragma unroll
  for (int ii = 0; ii < 4; ++ii) Og[ii * 64 + lane] = acc[ii];
}

// K3: u_path = relu(a1 + z2@W2 + a3 + bzz) + pe. grid = 256 (bi)
// lane = e; wave w owns j in [w*4, w*4+4). Broadcast = z-slice (LDS);
// per-lane W2 column from global (L2-hot, shared by all blocks).
__global__ __launch_bounds__(1024) void k_upath(
    const float* __restrict__ zt2, const float* __restrict__ Wzz,
    const float* __restrict__ bzz, const float* __restrict__ a1,
    const float* __restrict__ a3, const float* __restrict__ pe,
    float* __restrict__ out1) {
  int bi = blockIdx.x;
  int b = bi >> 6, i = bi & 63;
  int t = threadIdx.x, lane = t & 63, w = t >> 6;
  __shared__ float sZ[4096];              // [d][j] 16KB
  {
    int d2 = t >> 4, jo = (t & 15) * 4;   // gather z2[b][d][i][jo..jo+3]
    const float* src = zt2 + (size_t)b * 262144 + (size_t)d2 * 4096
                     + (size_t)i * 64 + jo;
    *(float4*)&sZ[d2 * 64 + jo] = *(const float4*)src;
  }
  // per-lane W2 column from global: wreg[d] = Wzz[64+d][e=lane]
  float wreg[64];
#pragma unroll
  for (int d = 0; d < 64; ++d) wreg[d] = Wzz[(64 + d) * 64 + lane];
  float base = a1[bi * 64 + lane] + bzz[lane];
  __syncthreads();
  int j0 = w * 4;
  float acc[4] = {base, base, base, base};
#pragma unroll
  for (int d = 0; d < 64; ++d) {
    const float4 z4 = *(const float4*)&sZ[d * 64 + j0];   // broadcast b128
    float wv = wreg[d];
    acc[0] += z4.x * wv;
    acc[1] += z4.y * wv;
    acc[2] += z4.z * wv;
    acc[3] += z4.w * wv;
  }
  const float* a3b = a3 + (size_t)b * 4096;
  size_t ob = (size_t)bi * 4096 + (size_t)j0 * 64;
#pragma unroll
  for (int jj = 0; jj < 4; ++jj) {
    float v = acc[jj] + a3b[(j0 + jj) * 64 + lane];
    v = fmaxf(v, 0.f);
    out1[ob + jj * 64 + lane] = v + pe[ob + jj * 64 + lane];
  }
}

extern "C" void kernel_launch(void* const* d_in, const int* in_sizes, int n_in,
                              void* d_out, int out_size, void* d_ws, size_t ws_size,
                              hipStream_t stream) {
  const float* node = (const float*)d_in[0];
  const float* pe   = (const float*)d_in[1];
  const int*   eidx = (const int*)d_in[2];
  const float* Whz  = (const float*)d_in[3];
  const float* bhz  = (const float*)d_in[4];
  const float* Wzz  = (const float*)d_in[5];
  const float* bzz  = (const float*)d_in[6];
  const float* Wnm  = (const float*)d_in[7];
  const float* bnm  = (const float*)d_in[8];
  float* out0 = (float*)d_out;
  float* out1 = out0 + 16384;
  float* zt  = (float*)d_ws;                // 4 MB
  float* zt2 = zt + 1048576;                // 4 MB
  float* a1  = zt2 + 1048576;               // 64 KB
  float* a3  = a1 + 16384;                  // 64 KB

  hipLaunchKernelGGL(k_pathlin_node, dim3(256), dim3(1024), 0, stream,
                     node, pe, eidx, Whz, bhz, Wzz, Wnm, bnm, zt, a1, a3, out0);
  hipLaunchKernelGGL(k_tropical, dim3(256), dim3(1024), 0, stream, zt, zt2);
  hipLaunchKernelGGL(k_upath, dim3(256), dim3(1024), 0, stream,
                     zt2, Wzz, bzz, a1, a3, pe, out1);
}

// Round 12
// 28.116 us; speedup vs baseline: 1.1404x; 1.1404x over previous
//
#include <hip/hip_runtime.h>

// Problem constants (b=4, n=64, d=64, E=4096)
// zt  layout: [b][d][i][k] -> ((b*64+d)*64+i)*64+k   (4 MB)
// zt2: tropical output, same layout (4 MB)
// a1[r][e], a3[r][e] : r = b*64+i (node row), 64 KB each
//
// R12 = R9 with K1 VERBATIM (proven 27.3); K2/K3 move the per-lane operand
// from LDS b32 to coalesced global loads (L1-hot) so DS and VMEM pipes split
// the load. Broadcast operand stays LDS ds_read_b128 (proven).

// K1: z = pe@Whz + bhz (transposed store) + node MLP + nodeproj. grid = 256 (bi)
__global__ __launch_bounds__(1024) void k_pathlin_node(
    const float* __restrict__ ne, const float* __restrict__ pe,
    const int* __restrict__ eidx,
    const float* __restrict__ Whz, const float* __restrict__ bhz,
    const float* __restrict__ Wzz,
    const float* __restrict__ Wnm, const float* __restrict__ bnm,
    float* __restrict__ zt, float* __restrict__ a1, float* __restrict__ a3,
    float* __restrict__ out0) {
  int bi = blockIdx.x;                    // b*64 + i == node row
  int b = bi >> 6, i = bi & 63;
  int t = threadIdx.x, lane = t & 63, w = t >> 6;   // 16 waves
  __shared__ float sP[4096];              // pe tile [k][c], 16KB
  __shared__ float sW[4096];              // Whz [c][d], 16KB
  __shared__ float part[16][64];
  __shared__ float nl[64], al[64];
  ((float4*)sP)[t] = ((const float4*)(pe + (size_t)bi * 4096))[t];
  ((float4*)sW)[t] = ((const float4*)Whz)[t];
  float bv = bhz[lane];
  if (w == 0) nl[lane] = ne[bi * 64 + lane];
  __syncthreads();
  // compute: lane = d, wave w owns k in [w*4, w*4+4)
  float acc[4] = {bv, bv, bv, bv};
  int k0 = w * 4;
#pragma unroll
  for (int c = 0; c < 64; c += 4) {
    float w0 = sW[(c + 0) * 64 + lane], w1 = sW[(c + 1) * 64 + lane];
    float w2 = sW[(c + 2) * 64 + lane], w3 = sW[(c + 3) * 64 + lane];
#pragma unroll
    for (int kk = 0; kk < 4; ++kk) {
      const float4 p = *(const float4*)&sP[(k0 + kk) * 64 + c];  // broadcast b128
      acc[kk] += p.x * w0 + p.y * w1 + p.z * w2 + p.w * w3;
    }
  }
  // transposed store: d = lane, 4 consecutive k -> one float4
  float* dst = zt + (size_t)b * 262144 + (size_t)lane * 4096 + (size_t)i * 64 + k0;
  *(float4*)dst = make_float4(acc[0], acc[1], acc[2], acc[3]);
  __syncthreads();                        // pe tile dead; alias as elist
  // ---- node MLP row bi: wave w scans edges [w*256, (w+1)*256) ----
  int* elist = (int*)sP;                  // 4096 ints = 16KB
  const int* srcv = eidx;
  const int* dstv = eidx + 4096;
  int cntw = 0;
  unsigned long long ltmask = (lane == 63) ? 0x7fffffffffffffffull
                                           : ((1ull << lane) - 1ull);
#pragma unroll
  for (int q = 0; q < 4; ++q) {
    int e2 = w * 256 + q * 64 + lane;
    bool match = (dstv[e2] == bi);
    unsigned long long mask = __ballot(match);
    if (match) {
      int pos = cntw + __popcll(mask & ltmask);
      elist[w * 256 + pos] = srcv[e2];
    }
    cntw += __popcll(mask);
  }
  float accA = 0.f;
  for (int m = 0; m < cntw; ++m) accA += ne[elist[w * 256 + m] * 64 + lane];
  part[w][lane] = accA;
  __syncthreads();
  if (w == 0) {
    float s = 0.f;
#pragma unroll
    for (int p2 = 0; p2 < 16; ++p2) s += part[p2][lane];
    al[lane] = s;
  } else if (w == 2) {                    // nodeproj a1
    const float* nr = ne + bi * 64;
    float s1 = 0.f;
    for (int d2 = 0; d2 < 64; ++d2) s1 += nr[d2] * Wzz[d2 * 64 + lane];
    a1[bi * 64 + lane] = s1;
  } else if (w == 3) {                    // nodeproj a3
    const float* nr = ne + bi * 64;
    float s3 = 0.f;
    for (int d2 = 0; d2 < 64; ++d2) s3 += nr[d2] * Wzz[(128 + d2) * 64 + lane];
    a3[bi * 64 + lane] = s3;
  }
  __syncthreads();
  // u_node partials: wave w handles d2 in [w*4, w*4+4)
  {
    float s = 0.f;
#pragma unroll
    for (int dd = 0; dd < 4; ++dd) {
      int d2 = w * 4 + dd;
      s += nl[d2] * Wnm[d2 * 64 + lane] + al[d2] * Wnm[(64 + d2) * 64 + lane];
    }
    part[w][lane] = s;
  }
  __syncthreads();
  if (w == 0) {
    float v = bnm[lane];
#pragma unroll
    for (int p2 = 0; p2 < 16; ++p2) v += part[p2][lane];
    v = fmaxf(v, 0.f);
    out0[bi * 64 + lane] = v + nl[lane];
  }
}

// K2: tropical max-plus per (b,d) slice. grid = 256 (slice)
// Broadcast rows from LDS (b128); per-lane column + acc-init from GLOBAL
// (coalesced, L1-hot) -> zero ds_read_b32 in the compute loop.
__global__ __launch_bounds__(1024) void k_tropical(
    const float* __restrict__ zt, float* __restrict__ zt2) {
  int slice = blockIdx.x;                 // b*64 + d
  int t = threadIdx.x, lane = t & 63, w = t >> 6;
  __shared__ float A[4096];               // 16KB slice for row broadcasts
  const float* Ag = zt + (size_t)slice * 4096;
  ((float4*)A)[t] = ((const float4*)Ag)[t];
  // per-lane column from global: colreg[k] = A[k][j=lane] (coalesced, L1-hot)
  float colreg[64];
#pragma unroll
  for (int k = 0; k < 64; ++k) colreg[k] = Ag[k * 64 + lane];
  int i0 = w * 4;
  float acc[4];
#pragma unroll
  for (int ii = 0; ii < 4; ++ii) acc[ii] = Ag[(i0 + ii) * 64 + lane];  // max(zc,z)
  __syncthreads();
#pragma unroll
  for (int k = 0; k < 64; k += 4) {
#pragma unroll
    for (int ii = 0; ii < 4; ++ii) {
      const float4 a = *(const float4*)&A[(i0 + ii) * 64 + k];   // broadcast b128
      float m0 = fmaxf(a.x + colreg[k], a.y + colreg[k + 1]);
      float m1 = fmaxf(a.z + colreg[k + 2], a.w + colreg[k + 3]);
      acc[ii] = fmaxf(acc[ii], fmaxf(m0, m1));
    }
  }
  float* Og = zt2 + (size_t)slice * 4096 + (size_t)i0 * 64;
#pragma unroll
  for (int ii = 0; ii < 4; ++ii) Og[ii * 64 + lane] = acc[ii];
}

// K3: u_path = relu(a1 + z2@W2 + a3 + bzz) + pe. grid = 256 (bi)
// Broadcast z-slice from LDS (b128); per-lane W2 column from GLOBAL
// (coalesced, L2-hot, shared by all 256 blocks) -> no W2 staging at all.
__global__ __launch_bounds__(1024) void k_upath(
    const float* __restrict__ zt2, const float* __restrict__ Wzz,
    const float* __restrict__ bzz, const float* __restrict__ a1,
    const float* __restrict__ a3, const float* __restrict__ pe,
    float* __restrict__ out1) {
  int bi = blockIdx.x;
  int b = bi >> 6, i = bi & 63;
  int t = threadIdx.x, lane = t & 63, w = t >> 6;
  __shared__ float sZ[4096];              // [d][j] 16KB
  {
    int d2 = t >> 4, jo = (t & 15) * 4;   // gather z2[b][d][i][jo..jo+3]
    const float* src = zt2 + (size_t)b * 262144 + (size_t)d2 * 4096
                     + (size_t)i * 64 + jo;
    *(float4*)&sZ[d2 * 64 + jo] = *(const float4*)src;
  }
  // per-lane W2 column from global: wreg[d] = Wzz[64+d][e=lane]
  float wreg[64];
#pragma unroll
  for (int d = 0; d < 64; ++d) wreg[d] = Wzz[(64 + d) * 64 + lane];
  float base = a1[bi * 64 + lane] + bzz[lane];
  __syncthreads();
  int j0 = w * 4;                         // wave w owns 4 consecutive j
  float acc[4] = {base, base, base, base};
#pragma unroll
  for (int d = 0; d < 64; ++d) {
    const float4 z4 = *(const float4*)&sZ[d * 64 + j0];   // broadcast b128
    float wv = wreg[d];
    acc[0] += z4.x * wv;
    acc[1] += z4.y * wv;
    acc[2] += z4.z * wv;
    acc[3] += z4.w * wv;
  }
  const float* a3b = a3 + (size_t)b * 4096;
  size_t ob = (size_t)bi * 4096 + (size_t)j0 * 64;
#pragma unroll
  for (int jj = 0; jj < 4; ++jj) {
    float v = acc[jj] + a3b[(j0 + jj) * 64 + lane];
    v = fmaxf(v, 0.f);
    out1[ob + jj * 64 + lane] = v + pe[ob + jj * 64 + lane];
  }
}

extern "C" void kernel_launch(void* const* d_in, const int* in_sizes, int n_in,
                              void* d_out, int out_size, void* d_ws, size_t ws_size,
                              hipStream_t stream) {
  const float* node = (const float*)d_in[0];
  const float* pe   = (const float*)d_in[1];
  const int*   eidx = (const int*)d_in[2];
  const float* Whz  = (const float*)d_in[3];
  const float* bhz  = (const float*)d_in[4];
  const float* Wzz  = (const float*)d_in[5];
  const float* bzz  = (const float*)d_in[6];
  const float* Wnm  = (const float*)d_in[7];
  const float* bnm  = (const float*)d_in[8];
  float* out0 = (float*)d_out;
  float* out1 = out0 + 16384;
  float* zt  = (float*)d_ws;                // 4 MB
  float* zt2 = zt + 1048576;                // 4 MB
  float* a1  = zt2 + 1048576;               // 64 KB
  float* a3  = a1 + 16384;                  // 64 KB

  hipLaunchKernelGGL(k_pathlin_node, dim3(256), dim3(1024), 0, stream,
                     node, pe, eidx, Whz, bhz, Wzz, Wnm, bnm, zt, a1, a3, out0);
  hipLaunchKernelGGL(k_tropical, dim3(256), dim3(1024), 0, stream, zt, zt2);
  hipLaunchKernelGGL(k_upath, dim3(256), dim3(1024), 0, stream,
                     zt2, Wzz, bzz, a1, a3, pe, out1);
}